// Round 6
// baseline (127.592 us; speedup 1.0000x reference)
//
#include <hip/hip_runtime.h>
#include <hip/hip_bf16.h>

typedef __bf16 v8bf __attribute__((ext_vector_type(8)));
typedef float f32x4 __attribute__((ext_vector_type(4)));
typedef float f32x16 __attribute__((ext_vector_type(16)));
typedef int v2i __attribute__((ext_vector_type(2)));
typedef int v4i __attribute__((ext_vector_type(4)));

#define MFMA16(a, b, c) __builtin_amdgcn_mfma_f32_16x16x32_bf16(a, b, c, 0, 0, 0)
#define MFMA32(a, b, c) __builtin_amdgcn_mfma_f32_32x32x16_bf16(a, b, c, 0, 0, 0)
#define GLOAD16(gp, lp)                                                        \
  __builtin_amdgcn_global_load_lds(                                            \
      (const __attribute__((address_space(1))) void*)(gp),                     \
      (__attribute__((address_space(3))) void*)(lp), 16, 0, 0)

// q scale = SCALE * log2(e) so that exp2(qk) == exp(qk*SCALE)
#define QSCALE 0.18033688011112042f

// ---------------- K0: weights -> MFMA-fragment-ordered bf16 ----------------
// wfrag[nb(6)][kk(8)][n(4)][lane(64)][8]: lane(g=l>>4,c=l&15) holds
//   wT row nb*64+n*16+c, cols kk*32+8g..+7  (wT = W^T; q part pre-scaled)
// owfrag[nb(4)][kk(8)][n(4)][lane][8] likewise for out_w^T.
__global__ __launch_bounds__(256) void k_cvt_w(const float* __restrict__ qw,
                                               const float* __restrict__ kw,
                                               const float* __restrict__ vw,
                                               const float* __restrict__ ow,
                                               __bf16* __restrict__ wfrag,
                                               __bf16* __restrict__ owfrag) {
  int t = blockIdx.x * 256 + threadIdx.x;  // 640*256 = 163840
  if (t < 98304) {
    int e = t & 7, idx = t >> 3;
    int l = idx & 63; idx >>= 6;
    int n = idx & 3; idx >>= 2;
    int kk = idx & 7, nb = idx >> 3;
    int nn = nb * 64 + n * 16 + (l & 15);
    int k = kk * 32 + 8 * (l >> 4) + e;
    float v;
    if (nn < 256) v = qw[k * 256 + nn] * QSCALE;
    else if (nn < 320) v = kw[k * 64 + (nn - 256)];
    else v = vw[k * 64 + (nn - 320)];
    wfrag[t] = (__bf16)v;
  } else {
    int u = t - 98304;
    int e = u & 7, idx = u >> 3;
    int l = idx & 63; idx >>= 6;
    int n = idx & 3; idx >>= 2;
    int kk = idx & 7, nb = idx >> 3;
    int nn = nb * 64 + n * 16 + (l & 15);
    int k = kk * 32 + 8 * (l >> 4) + e;
    owfrag[u] = (__bf16)ow[k * 256 + nn];
  }
}

// ---------------- K1: fused QKV projection GEMM ----------------
// M=32768, N=384, K=256. grid 1024 = 512 mb x 2 nh (3 N-tiles each);
// A-frags in registers (x read direct fp32->bf16); B-loads are dense
// fragment-ordered 16B/lane (zero address divergence).
__global__ __launch_bounds__(256) void k_qkv(const float* __restrict__ x,
                                             const __bf16* __restrict__ wfrag,
                                             const float* __restrict__ qb,
                                             const float* __restrict__ kb,
                                             const float* __restrict__ vb,
                                             __bf16* __restrict__ qo,
                                             __bf16* __restrict__ klin,
                                             __bf16* __restrict__ vlin) {
  int bx = blockIdx.x;
  int L = (bx & 7) * 128 + (bx >> 3);  // 1024 % 8 == 0: bijective XCD chunk
  int mb = L >> 1, nh = L & 1;         // nh inner: pair shares x rows on XCD
  int wave = threadIdx.x >> 6, lane = threadIdx.x & 63;
  int g = lane >> 4, c = lane & 15;
  int r0 = mb * 64 + wave * 16;
  const v8bf* wf = (const v8bf*)wfrag;

  v8bf a[8];
#pragma unroll
  for (int kk = 0; kk < 8; ++kk) {
    const float* ap = x + (size_t)(r0 + c) * 256 + kk * 32 + 8 * g;
    float4 f0 = *(const float4*)ap;
    float4 f1 = *(const float4*)(ap + 4);
    v8bf t;
    t[0] = (__bf16)f0.x; t[1] = (__bf16)f0.y; t[2] = (__bf16)f0.z; t[3] = (__bf16)f0.w;
    t[4] = (__bf16)f1.x; t[5] = (__bf16)f1.y; t[6] = (__bf16)f1.z; t[7] = (__bf16)f1.w;
    a[kk] = t;
  }
#pragma unroll
  for (int ni = 0; ni < 3; ++ni) {
    int nb = nh * 3 + ni;
    int n0 = nb * 64;
    f32x4 acc[4];
#pragma unroll
    for (int n = 0; n < 4; ++n) acc[n] = f32x4{0.f, 0.f, 0.f, 0.f};
#pragma unroll
    for (int kk = 0; kk < 8; ++kk) {
      v8bf bf[4];
#pragma unroll
      for (int n = 0; n < 4; ++n)
        bf[n] = wf[(((nb * 8 + kk) * 4 + n) << 6) | lane];
#pragma unroll
      for (int n = 0; n < 4; ++n) acc[n] = MFMA16(a[kk], bf[n], acc[n]);
    }
#pragma unroll
    for (int n = 0; n < 4; ++n) {
      int col = n0 + n * 16 + c;
      float bias;
      if (col < 256) bias = qb[col] * QSCALE;
      else if (col < 320) bias = kb[col - 256];
      else bias = vb[col - 320];
#pragma unroll
      for (int j = 0; j < 4; ++j) {
        int row = r0 + 4 * g + j;
        float v = acc[n][j] + bias;
        if (col < 256) qo[(size_t)row * 256 + col] = (__bf16)v;
        else if (col < 320) klin[(size_t)row * 64 + (col - 256)] = (__bf16)v;
        else vlin[(size_t)row * 64 + (col - 320)] = (__bf16)v;
      }
    }
  }
}

// ---------------- K2: depthwise 3x3 stride-2 conv on k,v ----------------
__global__ __launch_bounds__(256) void k_conv(const __bf16* __restrict__ klin,
                                              const __bf16* __restrict__ vlin,
                                              const float* __restrict__ kw,
                                              const float* __restrict__ kbias,
                                              const float* __restrict__ vw,
                                              const float* __restrict__ vbias,
                                              __bf16* __restrict__ kc,
                                              __bf16* __restrict__ vcT) {
  __shared__ __bf16 VT[32][66];
  int bx = blockIdx.x;
  int b = bx >> 5, pt = bx & 31;
  int t = threadIdx.x;
  int ch = t & 63, pg = t >> 6;
  float kwv[9], vwv[9];
#pragma unroll
  for (int i = 0; i < 9; ++i) { kwv[i] = kw[i * 64 + ch]; vwv[i] = vw[i * 64 + ch]; }
  float kb0 = kbias[ch], vb0 = vbias[ch];
  const __bf16* kin = klin + (size_t)b * 262144;
  const __bf16* vin = vlin + (size_t)b * 262144;
#pragma unroll
  for (int i = 0; i < 8; ++i) {
    int pl = pg * 8 + i;
    int p = pt * 32 + pl;
    int oy = p >> 5, ox = p & 31;
    float ak = kb0, av = vb0;
#pragma unroll
    for (int dy = 0; dy < 3; ++dy) {
      int iy = 2 * oy - 1 + dy;
      if (iy < 0 || iy > 63) continue;
#pragma unroll
      for (int dx = 0; dx < 3; ++dx) {
        int ix = 2 * ox - 1 + dx;
        if (ix < 0 || ix > 63) continue;
        size_t src = ((size_t)iy * 64 + ix) * 64 + ch;
        ak += (float)kin[src] * kwv[dy * 3 + dx];
        av += (float)vin[src] * vwv[dy * 3 + dx];
      }
    }
    kc[((size_t)b * 1024 + p) * 64 + ch] = (__bf16)ak;
    VT[pl][ch] = (__bf16)av;
  }
  __syncthreads();
  int row = t >> 2, c0 = (t & 3) * 8;
  __bf16 tmp[8];
#pragma unroll
  for (int i = 0; i < 8; ++i) tmp[i] = VT[c0 + i][row];
  *(v4i*)(vcT + (size_t)b * 65536 + row * 1024 + pt * 32 + c0) = *(v4i*)tmp;
}

// ---------------- K3: MQA flash attention, LDS-staged K/V ----------------
// grid 2048 (XCD-chunked by batch); 2 waves/block (128 thr), wave = 32 q rows.
// 8 blocks/CU resident (16KB LDS, VGPR<=128 via launch_bounds).
// exp2-direct softmax: logits pre-scaled by log2(e) in Q -> 1 v_exp per score.
__global__ __launch_bounds__(128, 4) void k_attn(const __bf16* __restrict__ q,
                                                 const __bf16* __restrict__ kc,
                                                 const __bf16* __restrict__ vcT,
                                                 __bf16* __restrict__ pv) {
  __shared__ __bf16 KV[8192];  // 2 buffers x (K 2048 + V 2048 elements)
  int bx = blockIdx.x;
  int L = (bx & 7) * 256 + (bx >> 3);  // 2048 % 8 == 0: bijective
  int b = L >> 8, hq = L & 255;
  int h = hq >> 6, qg = hq & 63;
  int wave = threadIdx.x >> 6, lane = threadIdx.x & 63;
  int c = lane & 31, hi = lane >> 5;
  int t = threadIdx.x;  // 0..127
  int qtile = qg * 2 + wave;
  size_t rowBase = (size_t)b * 4096 + qtile * 32;

  // staging: thread t stages chunks t and t+128 of the 256-chunk tile
  // K chunk u: kj = u>>5, kr = (u&31)^kj
  int kj0 = t >> 5, kr0 = (t & 31) ^ kj0;
  int kj1 = kj0 + 4, kr1 = (t & 31) ^ kj1;
  const __bf16* kg0 = kc + (size_t)b * 65536 + kr0 * 64 + kj0 * 8;
  const __bf16* kg1 = kc + (size_t)b * 65536 + kr1 * 64 + kj1 * 8;
  // V chunk u: dt=u>>7, ks=(u>>6)&1, vh=(u>>5)&1, cc=(u&31)^(ks*2+vh)
  int ks_ = (t >> 6) & 1, vh_ = (t >> 5) & 1;
  int cc = (t & 31) ^ (ks_ * 2 + vh_);
  const __bf16* vg0 = vcT + (size_t)b * 65536 + (size_t)cc * 1024 +
                      ks_ * 16 + vh_ * 8;           // dt=0
  const __bf16* vg1 = vg0 + 32768;                  // dt=1
  __bf16* kl0 = &KV[t * 8];
  __bf16* kl1 = kl0 + 1024;
  __bf16* vl0 = &KV[2048 + t * 8];
  __bf16* vl1 = vl0 + 1024;

  int Koff[4], Voff[2][2];
#pragma unroll
  for (int kk = 0; kk < 4; ++kk) {
    int j = kk * 2 + hi;
    Koff[kk] = (j * 32 + (c ^ j)) * 8;
  }
#pragma unroll
  for (int ks = 0; ks < 2; ++ks)
#pragma unroll
    for (int dt = 0; dt < 2; ++dt) {
      int j = ks * 2 + hi;
      Voff[ks][dt] = (256 + dt * 128 + ks * 64 + hi * 32 + (c ^ j)) * 8;
    }

  const __bf16* qbase = q + (rowBase + c) * 256 + h * 64 + hi * 8;
  v8bf Qf[4];
#pragma unroll
  for (int kk = 0; kk < 4; ++kk) Qf[kk] = *(const v8bf*)(qbase + kk * 16);

  f32x16 O0 = {}, O1 = {};
  const f32x16 Z16 = {};
  float ls0 = 0.f, ls1 = 0.f, ls2 = 0.f, ls3 = 0.f;

  GLOAD16(kg0, kl0);
  GLOAD16(kg1, kl1);
  GLOAD16(vg0, vl0);
  GLOAD16(vg1, vl1);
  __syncthreads();

  int buf = 0;
  for (int it = 0; it < 32; ++it) {
    const __bf16* base = &KV[buf * 4096];
    v8bf Kf[4], Vf[2][2];
#pragma unroll
    for (int kk = 0; kk < 4; ++kk) Kf[kk] = *(const v8bf*)(base + Koff[kk]);
#pragma unroll
    for (int ks = 0; ks < 2; ++ks)
#pragma unroll
      for (int dt = 0; dt < 2; ++dt)
        Vf[ks][dt] = *(const v8bf*)(base + Voff[ks][dt]);

    if (it < 31) {
      int nb = buf ^ 1;
      int koadv = (it + 1) * 2048, voadv = (it + 1) * 32;
      GLOAD16(kg0 + koadv, kl0 + nb * 4096);
      GLOAD16(kg1 + koadv, kl1 + nb * 4096);
      GLOAD16(vg0 + voadv, vl0 + nb * 4096);
      GLOAD16(vg1 + voadv, vl1 + nb * 4096);
    }

    f32x16 S = MFMA32(Kf[0], Qf[0], Z16);
    S = MFMA32(Kf[1], Qf[1], S);
    S = MFMA32(Kf[2], Qf[2], S);
    S = MFMA32(Kf[3], Qf[3], S);

    // exp2-direct: Q pre-scaled by log2(e) -> exp2(S) == softmax exp
    float p[16];
#pragma unroll
    for (int r = 0; r < 16; ++r) p[r] = __builtin_amdgcn_exp2f(S[r]);
    ls0 += (p[0] + p[1]) + (p[2] + p[3]);
    ls1 += (p[4] + p[5]) + (p[6] + p[7]);
    ls2 += (p[8] + p[9]) + (p[10] + p[11]);
    ls3 += (p[12] + p[13]) + (p[14] + p[15]);

    int w[8];
#pragma unroll
    for (int q2 = 0; q2 < 8; ++q2) {
      int r;
      asm("v_cvt_pk_bf16_f32 %0, %1, %2" : "=v"(r) : "v"(p[2 * q2]), "v"(p[2 * q2 + 1]));
      w[q2] = r;
    }
    v2i s1 = __builtin_amdgcn_permlane32_swap(w[2], w[0], false, false);
    v2i s2 = __builtin_amdgcn_permlane32_swap(w[3], w[1], false, false);
    v2i s3 = __builtin_amdgcn_permlane32_swap(w[6], w[4], false, false);
    v2i s4 = __builtin_amdgcn_permlane32_swap(w[7], w[5], false, false);
    v4i pa0i, pa1i;
    pa0i[0] = s1[1]; pa0i[1] = s2[1]; pa0i[2] = s1[0]; pa0i[3] = s2[0];
    pa1i[0] = s3[1]; pa1i[1] = s4[1]; pa1i[2] = s3[0]; pa1i[3] = s4[0];
    v8bf pa0 = *(v8bf*)&pa0i, pa1 = *(v8bf*)&pa1i;

    O0 = MFMA32(pa0, Vf[0][0], O0);
    O1 = MFMA32(pa0, Vf[0][1], O1);
    O0 = MFMA32(pa1, Vf[1][0], O0);
    O1 = MFMA32(pa1, Vf[1][1], O1);

    __syncthreads();
    buf ^= 1;
  }

  float lsum = (ls0 + ls1) + (ls2 + ls3);
  float tot = lsum + __shfl_xor(lsum, 32);
  float linv = 1.0f / tot;
  __bf16* op = pv + rowBase * 256 + h * 64;
#pragma unroll
  for (int r = 0; r < 16; ++r) {
    int qr = (r & 3) + 8 * (r >> 2) + 4 * hi;
    float li = __shfl(linv, qr);
    op[(size_t)qr * 256 + c] = (__bf16)(O0[r] * li);
    op[(size_t)qr * 256 + 32 + c] = (__bf16)(O1[r] * li);
  }
}

// ---------------- K4: output projection GEMM ----------------
// M=32768, N=256, K=256. grid 1024 = 512 mb x 2 nh (2 N-tiles each);
// dense fragment-ordered B loads.
__global__ __launch_bounds__(256) void k_out(const __bf16* __restrict__ pvb,
                                             const __bf16* __restrict__ owfrag,
                                             const float* __restrict__ ob,
                                             float* __restrict__ out) {
  int bx = blockIdx.x;
  int L = (bx & 7) * 128 + (bx >> 3);
  int mb = L >> 1, nh = L & 1;
  int wave = threadIdx.x >> 6, lane = threadIdx.x & 63;
  int g = lane >> 4, c = lane & 15;
  int r0 = mb * 64 + wave * 16;
  const v8bf* wf = (const v8bf*)owfrag;

  v8bf a[8];
#pragma unroll
  for (int kk = 0; kk < 8; ++kk)
    a[kk] = *(const v8bf*)(pvb + (size_t)(r0 + c) * 256 + kk * 32 + 8 * g);
#pragma unroll
  for (int ni = 0; ni < 2; ++ni) {
    int nb = nh * 2 + ni;
    int n0 = nb * 64;
    f32x4 acc[4];
#pragma unroll
    for (int n = 0; n < 4; ++n) acc[n] = f32x4{0.f, 0.f, 0.f, 0.f};
#pragma unroll
    for (int kk = 0; kk < 8; ++kk) {
      v8bf bf[4];
#pragma unroll
      for (int n = 0; n < 4; ++n)
        bf[n] = wf[(((nb * 8 + kk) * 4 + n) << 6) | lane];
#pragma unroll
      for (int n = 0; n < 4; ++n) acc[n] = MFMA16(a[kk], bf[n], acc[n]);
    }
#pragma unroll
    for (int n = 0; n < 4; ++n) {
      int col = n0 + n * 16 + c;
      float bias = ob[col];
#pragma unroll
      for (int j = 0; j < 4; ++j) {
        int row = r0 + 4 * g + j;
        out[(size_t)row * 256 + col] = acc[n][j] + bias;
      }
    }
  }
}

// ---------------- launcher ----------------
extern "C" void kernel_launch(void* const* d_in, const int* in_sizes, int n_in,
                              void* d_out, int out_size, void* d_ws, size_t ws_size,
                              hipStream_t stream) {
  const float* x   = (const float*)d_in[0];
  const float* qw  = (const float*)d_in[1];
  const float* qb  = (const float*)d_in[2];
  const float* kw  = (const float*)d_in[3];
  const float* kb  = (const float*)d_in[4];
  const float* vw  = (const float*)d_in[5];
  const float* vb  = (const float*)d_in[6];
  const float* kcw = (const float*)d_in[7];
  const float* kcb = (const float*)d_in[8];
  const float* vcw = (const float*)d_in[9];
  const float* vcb = (const float*)d_in[10];
  const float* ow  = (const float*)d_in[11];
  const float* ob  = (const float*)d_in[12];
  float* out = (float*)d_out;
  char* ws = (char*)d_ws;

  __bf16* pv     = (__bf16*)(ws + 0);          // 16,777,216
  __bf16* qbuf   = (__bf16*)(ws + 16777216);   // 16,777,216
  __bf16* klin   = (__bf16*)(ws + 33554432);   //  4,194,304
  __bf16* vlin   = (__bf16*)(ws + 37748736);   //  4,194,304
  __bf16* kc     = (__bf16*)(ws + 41943040);   //  1,048,576
  __bf16* vcT    = (__bf16*)(ws + 42991616);   //  1,048,576
  __bf16* wfrag  = (__bf16*)(ws + 44040192);   //    196,608
  __bf16* owfrag = (__bf16*)(ws + 44236800);   //    131,072

  k_cvt_w<<<640, 256, 0, stream>>>(qw, kw, vw, ow, wfrag, owfrag);
  k_qkv<<<1024, 256, 0, stream>>>(x, wfrag, qb, kb, vb, qbuf, klin, vlin);
  k_conv<<<256, 256, 0, stream>>>(klin, vlin, kcw, kcb, vcw, vcb, kc, vcT);
  k_attn<<<2048, 128, 0, stream>>>(qbuf, kc, vcT, pv);
  k_out<<<1024, 256, 0, stream>>>(pv, owfrag, ob, out);
}

// Round 7
// 106.475 us; speedup vs baseline: 1.1983x; 1.1983x over previous
//
#include <hip/hip_runtime.h>
#include <hip/hip_bf16.h>

typedef __bf16 v8bf __attribute__((ext_vector_type(8)));
typedef float f32x4 __attribute__((ext_vector_type(4)));
typedef float f32x16 __attribute__((ext_vector_type(16)));
typedef int v2i __attribute__((ext_vector_type(2)));
typedef int v4i __attribute__((ext_vector_type(4)));

#define MFMA16(a, b, c) __builtin_amdgcn_mfma_f32_16x16x32_bf16(a, b, c, 0, 0, 0)
#define MFMA32(a, b, c) __builtin_amdgcn_mfma_f32_32x32x16_bf16(a, b, c, 0, 0, 0)
#define GLOAD16(gp, lp)                                                        \
  __builtin_amdgcn_global_load_lds(                                            \
      (const __attribute__((address_space(1))) void*)(gp),                     \
      (__attribute__((address_space(3))) void*)(lp), 16, 0, 0)

// q scale = SCALE * log2(e) so that exp2(qk) == exp(qk*SCALE)
#define QSCALE 0.18033688011112042f

// ---------------- K0: weights -> MFMA-fragment-ordered bf16 ----------------
// wfrag[nb(6)][kk(8)][n(4)][lane(64)][8]: lane(g=l>>4,c=l&15) holds
//   wT row nb*64+n*16+c, cols kk*32+8g..+7  (wT = W^T; q part pre-scaled)
// owfrag[nb(4)][kk(8)][n(4)][lane][8] likewise for out_w^T.
__global__ __launch_bounds__(256) void k_cvt_w(const float* __restrict__ qw,
                                               const float* __restrict__ kw,
                                               const float* __restrict__ vw,
                                               const float* __restrict__ ow,
                                               __bf16* __restrict__ wfrag,
                                               __bf16* __restrict__ owfrag) {
  int t = blockIdx.x * 256 + threadIdx.x;  // 640*256 = 163840
  if (t < 98304) {
    int e = t & 7, idx = t >> 3;
    int l = idx & 63; idx >>= 6;
    int n = idx & 3; idx >>= 2;
    int kk = idx & 7, nb = idx >> 3;
    int nn = nb * 64 + n * 16 + (l & 15);
    int k = kk * 32 + 8 * (l >> 4) + e;
    float v;
    if (nn < 256) v = qw[k * 256 + nn] * QSCALE;
    else if (nn < 320) v = kw[k * 64 + (nn - 256)];
    else v = vw[k * 64 + (nn - 320)];
    wfrag[t] = (__bf16)v;
  } else {
    int u = t - 98304;
    int e = u & 7, idx = u >> 3;
    int l = idx & 63; idx >>= 6;
    int n = idx & 3; idx >>= 2;
    int kk = idx & 7, nb = idx >> 3;
    int nn = nb * 64 + n * 16 + (l & 15);
    int k = kk * 32 + 8 * (l >> 4) + e;
    owfrag[u] = (__bf16)ow[k * 256 + nn];
  }
}

// ---------------- K1: fused QKV projection GEMM ----------------
// M=32768, N=384, K=256. grid 1024 = 512 mb x 2 nh (3 N-tiles each);
// A-frags in registers (x read direct fp32->bf16); B-loads are dense
// fragment-ordered 16B/lane (zero address divergence).
__global__ __launch_bounds__(256) void k_qkv(const float* __restrict__ x,
                                             const __bf16* __restrict__ wfrag,
                                             const float* __restrict__ qb,
                                             const float* __restrict__ kb,
                                             const float* __restrict__ vb,
                                             __bf16* __restrict__ qo,
                                             __bf16* __restrict__ klin,
                                             __bf16* __restrict__ vlin) {
  int bx = blockIdx.x;
  int L = (bx & 7) * 128 + (bx >> 3);  // 1024 % 8 == 0: bijective XCD chunk
  int mb = L >> 1, nh = L & 1;         // nh inner: pair shares x rows on XCD
  int wave = threadIdx.x >> 6, lane = threadIdx.x & 63;
  int g = lane >> 4, c = lane & 15;
  int r0 = mb * 64 + wave * 16;
  const v8bf* wf = (const v8bf*)wfrag;

  v8bf a[8];
#pragma unroll
  for (int kk = 0; kk < 8; ++kk) {
    const float* ap = x + (size_t)(r0 + c) * 256 + kk * 32 + 8 * g;
    float4 f0 = *(const float4*)ap;
    float4 f1 = *(const float4*)(ap + 4);
    v8bf t;
    t[0] = (__bf16)f0.x; t[1] = (__bf16)f0.y; t[2] = (__bf16)f0.z; t[3] = (__bf16)f0.w;
    t[4] = (__bf16)f1.x; t[5] = (__bf16)f1.y; t[6] = (__bf16)f1.z; t[7] = (__bf16)f1.w;
    a[kk] = t;
  }
#pragma unroll
  for (int ni = 0; ni < 3; ++ni) {
    int nb = nh * 3 + ni;
    int n0 = nb * 64;
    f32x4 acc[4];
#pragma unroll
    for (int n = 0; n < 4; ++n) acc[n] = f32x4{0.f, 0.f, 0.f, 0.f};
#pragma unroll
    for (int kk = 0; kk < 8; ++kk) {
      v8bf bf[4];
#pragma unroll
      for (int n = 0; n < 4; ++n)
        bf[n] = wf[(((nb * 8 + kk) * 4 + n) << 6) | lane];
#pragma unroll
      for (int n = 0; n < 4; ++n) acc[n] = MFMA16(a[kk], bf[n], acc[n]);
    }
#pragma unroll
    for (int n = 0; n < 4; ++n) {
      int col = n0 + n * 16 + c;
      float bias;
      if (col < 256) bias = qb[col] * QSCALE;
      else if (col < 320) bias = kb[col - 256];
      else bias = vb[col - 320];
#pragma unroll
      for (int j = 0; j < 4; ++j) {
        int row = r0 + 4 * g + j;
        float v = acc[n][j] + bias;
        if (col < 256) qo[(size_t)row * 256 + col] = (__bf16)v;
        else if (col < 320) klin[(size_t)row * 64 + (col - 256)] = (__bf16)v;
        else vlin[(size_t)row * 64 + (col - 320)] = (__bf16)v;
      }
    }
  }
}

// ---------------- K2: depthwise 3x3 stride-2 conv on k,v ----------------
__global__ __launch_bounds__(256) void k_conv(const __bf16* __restrict__ klin,
                                              const __bf16* __restrict__ vlin,
                                              const float* __restrict__ kw,
                                              const float* __restrict__ kbias,
                                              const float* __restrict__ vw,
                                              const float* __restrict__ vbias,
                                              __bf16* __restrict__ kc,
                                              __bf16* __restrict__ vcT) {
  __shared__ __bf16 VT[32][66];
  int bx = blockIdx.x;
  int b = bx >> 5, pt = bx & 31;
  int t = threadIdx.x;
  int ch = t & 63, pg = t >> 6;
  float kwv[9], vwv[9];
#pragma unroll
  for (int i = 0; i < 9; ++i) { kwv[i] = kw[i * 64 + ch]; vwv[i] = vw[i * 64 + ch]; }
  float kb0 = kbias[ch], vb0 = vbias[ch];
  const __bf16* kin = klin + (size_t)b * 262144;
  const __bf16* vin = vlin + (size_t)b * 262144;
#pragma unroll
  for (int i = 0; i < 8; ++i) {
    int pl = pg * 8 + i;
    int p = pt * 32 + pl;
    int oy = p >> 5, ox = p & 31;
    float ak = kb0, av = vb0;
#pragma unroll
    for (int dy = 0; dy < 3; ++dy) {
      int iy = 2 * oy - 1 + dy;
      if (iy < 0 || iy > 63) continue;
#pragma unroll
      for (int dx = 0; dx < 3; ++dx) {
        int ix = 2 * ox - 1 + dx;
        if (ix < 0 || ix > 63) continue;
        size_t src = ((size_t)iy * 64 + ix) * 64 + ch;
        ak += (float)kin[src] * kwv[dy * 3 + dx];
        av += (float)vin[src] * vwv[dy * 3 + dx];
      }
    }
    kc[((size_t)b * 1024 + p) * 64 + ch] = (__bf16)ak;
    VT[pl][ch] = (__bf16)av;
  }
  __syncthreads();
  int row = t >> 2, c0 = (t & 3) * 8;
  __bf16 tmp[8];
#pragma unroll
  for (int i = 0; i < 8; ++i) tmp[i] = VT[c0 + i][row];
  *(v4i*)(vcT + (size_t)b * 65536 + row * 1024 + pt * 32 + c0) = *(v4i*)tmp;
}

// ---------------- K3: MQA flash attention, LDS-staged K/V ----------------
// grid 1024 (XCD-chunked by batch); 4 waves/block (256 thr), wave = 32 q rows.
// exp2-direct softmax (Q pre-scaled by log2(e)), tree-structured l-sums.
__global__ __launch_bounds__(256) void k_attn(const __bf16* __restrict__ q,
                                              const __bf16* __restrict__ kc,
                                              const __bf16* __restrict__ vcT,
                                              __bf16* __restrict__ pv) {
  __shared__ __bf16 KV[8192];  // 2 buffers x (K 2048 + V 2048 elements)
  int bx = blockIdx.x;
  int L = (bx & 7) * 128 + (bx >> 3);
  int b = L >> 7, hq = L & 127;
  int h = hq >> 5, qg = hq & 31;
  int wave = threadIdx.x >> 6, lane = threadIdx.x & 63;
  int c = lane & 31, hi = lane >> 5;
  int t = threadIdx.x;
  int qtile = qg * 4 + wave;
  size_t rowBase = (size_t)b * 4096 + qtile * 32;

  // staging source pointers (pre-swizzled global, linear LDS)
  int kj = t >> 5, kr = (t & 31) ^ kj;
  const __bf16* kg = kc + (size_t)b * 65536 + kr * 64 + kj * 8;
  int dt_ = t >> 7, ks_ = (t >> 6) & 1, vh_ = (t >> 5) & 1;
  int cc = (t & 31) ^ (ks_ * 2 + vh_);
  const __bf16* vg = vcT + (size_t)b * 65536 + (size_t)(dt_ * 32 + cc) * 1024 +
                     ks_ * 16 + vh_ * 8;
  __bf16* kl = &KV[t * 8];
  __bf16* vl = &KV[2048 + t * 8];

  int Koff[4], Voff[2][2];
#pragma unroll
  for (int kk = 0; kk < 4; ++kk) {
    int j = kk * 2 + hi;
    Koff[kk] = (j * 32 + (c ^ j)) * 8;
  }
#pragma unroll
  for (int ks = 0; ks < 2; ++ks)
#pragma unroll
    for (int dt = 0; dt < 2; ++dt) {
      int j = ks * 2 + hi;
      Voff[ks][dt] = (256 + dt * 128 + ks * 64 + hi * 32 + (c ^ j)) * 8;
    }

  const __bf16* qbase = q + (rowBase + c) * 256 + h * 64 + hi * 8;
  v8bf Qf[4];
#pragma unroll
  for (int kk = 0; kk < 4; ++kk) Qf[kk] = *(const v8bf*)(qbase + kk * 16);

  f32x16 O0 = {}, O1 = {};
  const f32x16 Z16 = {};
  float ls0 = 0.f, ls1 = 0.f, ls2 = 0.f, ls3 = 0.f;

  GLOAD16(kg, kl);
  GLOAD16(vg, vl);
  __syncthreads();

  int buf = 0;
  for (int it = 0; it < 32; ++it) {
    const __bf16* base = &KV[buf * 4096];
    v8bf Kf[4], Vf[2][2];
#pragma unroll
    for (int kk = 0; kk < 4; ++kk) Kf[kk] = *(const v8bf*)(base + Koff[kk]);
#pragma unroll
    for (int ks = 0; ks < 2; ++ks)
#pragma unroll
      for (int dt = 0; dt < 2; ++dt)
        Vf[ks][dt] = *(const v8bf*)(base + Voff[ks][dt]);

    if (it < 31) {
      int nb = buf ^ 1;
      GLOAD16(kg + (it + 1) * 2048, kl + nb * 4096);
      GLOAD16(vg + (it + 1) * 32, vl + nb * 4096);
    }

    f32x16 S = MFMA32(Kf[0], Qf[0], Z16);
    S = MFMA32(Kf[1], Qf[1], S);
    S = MFMA32(Kf[2], Qf[2], S);
    S = MFMA32(Kf[3], Qf[3], S);

    // exp2-direct: Q pre-scaled by log2(e) -> exp2(S) == softmax exp
    float p[16];
#pragma unroll
    for (int r = 0; r < 16; ++r) p[r] = __builtin_amdgcn_exp2f(S[r]);
    ls0 += (p[0] + p[1]) + (p[2] + p[3]);
    ls1 += (p[4] + p[5]) + (p[6] + p[7]);
    ls2 += (p[8] + p[9]) + (p[10] + p[11]);
    ls3 += (p[12] + p[13]) + (p[14] + p[15]);

    int w[8];
#pragma unroll
    for (int q2 = 0; q2 < 8; ++q2) {
      int r;
      asm("v_cvt_pk_bf16_f32 %0, %1, %2" : "=v"(r) : "v"(p[2 * q2]), "v"(p[2 * q2 + 1]));
      w[q2] = r;
    }
    v2i s1 = __builtin_amdgcn_permlane32_swap(w[2], w[0], false, false);
    v2i s2 = __builtin_amdgcn_permlane32_swap(w[3], w[1], false, false);
    v2i s3 = __builtin_amdgcn_permlane32_swap(w[6], w[4], false, false);
    v2i s4 = __builtin_amdgcn_permlane32_swap(w[7], w[5], false, false);
    v4i pa0i, pa1i;
    pa0i[0] = s1[1]; pa0i[1] = s2[1]; pa0i[2] = s1[0]; pa0i[3] = s2[0];
    pa1i[0] = s3[1]; pa1i[1] = s4[1]; pa1i[2] = s3[0]; pa1i[3] = s4[0];
    v8bf pa0 = *(v8bf*)&pa0i, pa1 = *(v8bf*)&pa1i;

    O0 = MFMA32(pa0, Vf[0][0], O0);
    O1 = MFMA32(pa0, Vf[0][1], O1);
    O0 = MFMA32(pa1, Vf[1][0], O0);
    O1 = MFMA32(pa1, Vf[1][1], O1);

    __syncthreads();
    buf ^= 1;
  }

  float lsum = (ls0 + ls1) + (ls2 + ls3);
  float tot = lsum + __shfl_xor(lsum, 32);
  float linv = 1.0f / tot;
  __bf16* op = pv + rowBase * 256 + h * 64;
#pragma unroll
  for (int r = 0; r < 16; ++r) {
    int qr = (r & 3) + 8 * (r >> 2) + 4 * hi;
    float li = __shfl(linv, qr);
    op[(size_t)qr * 256 + c] = (__bf16)(O0[r] * li);
    op[(size_t)qr * 256 + 32 + c] = (__bf16)(O1[r] * li);
  }
}

// ---------------- K4: output projection GEMM ----------------
// M=32768, N=256, K=256. grid 1024 = 512 mb x 2 nh (2 N-tiles each);
// dense fragment-ordered B loads.
__global__ __launch_bounds__(256) void k_out(const __bf16* __restrict__ pvb,
                                             const __bf16* __restrict__ owfrag,
                                             const float* __restrict__ ob,
                                             float* __restrict__ out) {
  int bx = blockIdx.x;
  int L = (bx & 7) * 128 + (bx >> 3);
  int mb = L >> 1, nh = L & 1;
  int wave = threadIdx.x >> 6, lane = threadIdx.x & 63;
  int g = lane >> 4, c = lane & 15;
  int r0 = mb * 64 + wave * 16;
  const v8bf* wf = (const v8bf*)owfrag;

  v8bf a[8];
#pragma unroll
  for (int kk = 0; kk < 8; ++kk)
    a[kk] = *(const v8bf*)(pvb + (size_t)(r0 + c) * 256 + kk * 32 + 8 * g);
#pragma unroll
  for (int ni = 0; ni < 2; ++ni) {
    int nb = nh * 2 + ni;
    int n0 = nb * 64;
    f32x4 acc[4];
#pragma unroll
    for (int n = 0; n < 4; ++n) acc[n] = f32x4{0.f, 0.f, 0.f, 0.f};
#pragma unroll
    for (int kk = 0; kk < 8; ++kk) {
      v8bf bf[4];
#pragma unroll
      for (int n = 0; n < 4; ++n)
        bf[n] = wf[(((nb * 8 + kk) * 4 + n) << 6) | lane];
#pragma unroll
      for (int n = 0; n < 4; ++n) acc[n] = MFMA16(a[kk], bf[n], acc[n]);
    }
#pragma unroll
    for (int n = 0; n < 4; ++n) {
      int col = n0 + n * 16 + c;
      float bias = ob[col];
#pragma unroll
      for (int j = 0; j < 4; ++j) {
        int row = r0 + 4 * g + j;
        out[(size_t)row * 256 + col] = acc[n][j] + bias;
      }
    }
  }
}

// ---------------- launcher ----------------
extern "C" void kernel_launch(void* const* d_in, const int* in_sizes, int n_in,
                              void* d_out, int out_size, void* d_ws, size_t ws_size,
                              hipStream_t stream) {
  const float* x   = (const float*)d_in[0];
  const float* qw  = (const float*)d_in[1];
  const float* qb  = (const float*)d_in[2];
  const float* kw  = (const float*)d_in[3];
  const float* kb  = (const float*)d_in[4];
  const float* vw  = (const float*)d_in[5];
  const float* vb  = (const float*)d_in[6];
  const float* kcw = (const float*)d_in[7];
  const float* kcb = (const float*)d_in[8];
  const float* vcw = (const float*)d_in[9];
  const float* vcb = (const float*)d_in[10];
  const float* ow  = (const float*)d_in[11];
  const float* ob  = (const float*)d_in[12];
  float* out = (float*)d_out;
  char* ws = (char*)d_ws;

  __bf16* pv     = (__bf16*)(ws + 0);          // 16,777,216
  __bf16* qbuf   = (__bf16*)(ws + 16777216);   // 16,777,216
  __bf16* klin   = (__bf16*)(ws + 33554432);   //  4,194,304
  __bf16* vlin   = (__bf16*)(ws + 37748736);   //  4,194,304
  __bf16* kc     = (__bf16*)(ws + 41943040);   //  1,048,576
  __bf16* vcT    = (__bf16*)(ws + 42991616);   //  1,048,576
  __bf16* wfrag  = (__bf16*)(ws + 44040192);   //    196,608
  __bf16* owfrag = (__bf16*)(ws + 44236800);   //    131,072

  k_cvt_w<<<640, 256, 0, stream>>>(qw, kw, vw, ow, wfrag, owfrag);
  k_qkv<<<1024, 256, 0, stream>>>(x, wfrag, qb, kb, vb, qbuf, klin, vlin);
  k_conv<<<256, 256, 0, stream>>>(klin, vlin, kcw, kcb, vcw, vcb, kc, vcT);
  k_attn<<<1024, 256, 0, stream>>>(qbuf, kc, vcT, pv);
  k_out<<<1024, 256, 0, stream>>>(pv, owfrag, ob, out);
}